// Round 7
// baseline (105.432 us; speedup 1.0000x reference)
//
#include <hip/hip_runtime.h>

// AdaptiveHighPassFilter: conv3x3(64->9, zero-pad) -> softmax(taps) -> hamming
// renorm -> CARAFE(3x3, reflect) -> 2x - lowpass.
//
// R7 vs R6 (~40us, latency/phase-serialization-bound):
//  - ONE WAVE PER BLOCK (64 thr, 16x4 tile, TPY=6, LDS 15.5KB): no cross-wave
//    barrier rendezvous; each wave free-runs stage->conv->carafe, so the ~8
//    resident waves/CU stay phase-staggered and hide each other's latency.
//  - 2048 blocks, XCD swizzle kept (R4 evidence: FETCH 57->19MB).
//  - staging global loads issued before the afr L2 loads (HBM long-pole first).
//  - carafe from conv B-fragment registers + shuffle mask broadcast (R6).
//  - weights pre-fragmented into d_ws by prep kernel; A-frags = 18 coalesced
//    dwordx4 loads. CSH=72: B-frag ds_read pattern is exactly 8 dwords/bank.

typedef __attribute__((ext_vector_type(8))) short short8;
typedef __attribute__((ext_vector_type(4))) float floatx4;
typedef __attribute__((ext_vector_type(4))) unsigned uint4v;
typedef __attribute__((ext_vector_type(2))) float float2v;

#define IH 128
#define IW 128
#define CCH 64
#define TSX 16
#define TSY 4
#define TPX 18
#define TPY 6
#define CSH 72   // shorts per position: 144B row, 16B-aligned, bank stride 4

__device__ __forceinline__ unsigned short f2bf(float f) {
    unsigned u = __float_as_uint(f);
    u += 0x7FFFu + ((u >> 16) & 1u);     // round-to-nearest-even
    return (unsigned short)(u >> 16);
}
__device__ __forceinline__ unsigned pkbf(float a, float b) {
    return (unsigned)f2bf(a) | ((unsigned)f2bf(b) << 16);
}
__device__ __forceinline__ float2v unpk(unsigned u) {
    float2v r;
    r.x = __uint_as_float(u << 16);
    r.y = __uint_as_float(u & 0xFFFF0000u);
    return r;
}

// ---- prep: W[9][64][3][3] f32 -> bf16 A-fragments ws[s][lane][8shorts]
__global__ void ahpf_prep(const float* __restrict__ Wg,
                          unsigned short* __restrict__ wsp)
{
    const int i = blockIdx.x * 256 + threadIdx.x;   // 0..1151
    if (i >= 18 * 64) return;
    const int s = i >> 6, l = i & 63;
    const int fm = l & 15, fq = l >> 4;
    const int tap = s >> 1, cb = (s & 1) * 32 + fq * 8;
    short8 v = (short8)0;
    if (fm < 9) {
#pragma unroll
        for (int jj = 0; jj < 8; ++jj)
            v[jj] = (short)f2bf(Wg[fm * 576 + (cb + jj) * 9 + tap]);
    }
    ((short8*)wsp)[i] = v;
}

template <bool USE_WS>
__global__ __launch_bounds__(64, 2) void ahpf_kernel(
    const float* __restrict__ x, const float* __restrict__ Wg,
    const float* __restrict__ bias, float* __restrict__ out,
    const unsigned short* __restrict__ wsp)
{
    __shared__ __align__(16) unsigned short sx[TPY * TPX * CSH];  // 15,552 B

    const int lane = threadIdx.x;

    // XCD swizzle: XCD k gets the 256 tiles of image k
    const unsigned flat = blockIdx.x;
    const unsigned nid  = (flat & 7u) * 256u + (flat >> 3);
    const int bx = nid & 7, by = (nid >> 3) & 31, bz = nid >> 8;

    const int ty0 = by * TSY;
    const int tx0 = bx * TSX;
    const size_t hw = (size_t)IH * IW;
    const float* xb = x + (size_t)bz * CCH * hw;

    const int fm = lane & 15;   // conv: pixel col n / A row m
    const int fq = lane >> 4;

    // ---- stage reflect-padded tile bf16 [pos][c]; slot = 8ch x 4pos.
    // 288 slots (6y x 6xg x 8cg) over 64 lanes = 4.5 iterations.
    {
        int gx0 = tx0 - 4;
        if (gx0 < 0) gx0 = 0;
        if (gx0 > IW - 24) gx0 = IW - 24;
        const bool xlo = (bx == 0), xhi = (bx == 7);
        const int cg8 = lane & 7;                // fixed per lane
#pragma unroll
        for (int it = 0; it < 5; ++it) {
            const int s = it * 64 + lane;        // 288 slots total
            if (s >= TPY * 6 * 8) break;
            const int u = s >> 3;                // 0..35
            const int y = u / 6, xg = u - 6 * y;
            int gy = ty0 + y - 1;
            gy = gy < 0 ? -gy : (gy >= IH ? 2 * IH - 2 - gy : gy);
            const float* src = xb + (size_t)(cg8 * 8) * hw
                             + (size_t)gy * IW + gx0 + 4 * xg;
            float4 v[8];
#pragma unroll
            for (int jj = 0; jj < 8; ++jj)
                v[jj] = *(const float4*)(src + (size_t)jj * hw);
            const int xbase = gx0 + 4 * xg - tx0 + 1;
#pragma unroll
            for (int e = 0; e < 4; ++e) {
                const float fe[8] = {
                    ((const float*)&v[0])[e], ((const float*)&v[1])[e],
                    ((const float*)&v[2])[e], ((const float*)&v[3])[e],
                    ((const float*)&v[4])[e], ((const float*)&v[5])[e],
                    ((const float*)&v[6])[e], ((const float*)&v[7])[e]};
                uint4v pk;
                pk.x = pkbf(fe[0], fe[1]); pk.y = pkbf(fe[2], fe[3]);
                pk.z = pkbf(fe[4], fe[5]); pk.w = pkbf(fe[6], fe[7]);
                const int gxe = gx0 + 4 * xg + e;
                const int xx = xbase + e;
                if (xx >= 0 && xx < TPX)
                    *(uint4v*)&sx[(y * TPX + xx) * CSH + cg8 * 8] = pk;
                if (xlo && gxe == 1)
                    *(uint4v*)&sx[(y * TPX + 0) * CSH + cg8 * 8] = pk;
                if (xhi && gxe == 126)
                    *(uint4v*)&sx[(y * TPX + 17) * CSH + cg8 * 8] = pk;
            }
        }
    }

    // ---- A-fragments: 18 coalesced b128 loads (L2-hot), after HBM issues
    short8 afr[18];
    if (USE_WS) {
        const short8* wf = (const short8*)wsp;
#pragma unroll
        for (int s = 0; s < 18; ++s) afr[s] = wf[s * 64 + lane];
    } else {
#pragma unroll
        for (int s = 0; s < 18; ++s) {
            short8 a = (short8)0;
            if (fm < 9) {
                const int tap = s >> 1, cb = (s & 1) * 32 + fq * 8;
                const float* wp = Wg + fm * 576 + tap;
#pragma unroll
                for (int jj = 0; jj < 8; ++jj)
                    a[jj] = (short)f2bf(wp[(cb + jj) * 9]);
            }
            afr[s] = a;
        }
    }
    float bq[4];
#pragma unroll
    for (int r = 0; r < 4; ++r) {
        const int t = fq * 4 + r;
        bq[r] = (t < 9) ? bias[t] : 0.0f;
    }
    __syncthreads();   // single wave: just the waitcnt drain, no rendezvous

    const bool border = (bx == 0) | (bx == 7) | (by == 0) | (by == 31);
    const int n = fm;

    // ---- per row: conv MFMA -> softmax -> mask broadcast -> carafe from regs
    for (int R = 0; R < TSY; ++R) {
        const int h = ty0 + R, w = tx0 + n;

        short8 bfr[18];
#pragma unroll
        for (int s = 0; s < 18; ++s) {
            const int tap = s >> 1;
            const int dy = tap / 3 - 1, dx = tap % 3 - 1;
            bfr[s] = *(const short8*)&sx[((R + 1 + dy) * TPX + (n + 1 + dx)) * CSH
                                         + (s & 1) * 32 + fq * 8];
        }

        floatx4 acc = {0.f, 0.f, 0.f, 0.f};
        if (border) {
#pragma unroll
            for (int s = 0; s < 18; ++s) {
                const int tap = s >> 1;
                const int dy = tap / 3 - 1, dx = tap % 3 - 1;
                const int hy = h + dy, wx = w + dx;
                short8 bb = bfr[s];
                if (hy < 0 || hy >= IH || wx < 0 || wx >= IW) bb = (short8)0;
                acc = __builtin_amdgcn_mfma_f32_16x16x32_bf16(afr[s], bb, acc, 0, 0, 0);
            }
        } else {
#pragma unroll
            for (int s = 0; s < 18; ++s)
                acc = __builtin_amdgcn_mfma_f32_16x16x32_bf16(afr[s], bfr[s], acc, 0, 0, 0);
        }

        // softmax*hamming, denom-cancelled; lane holds taps fq*4+r of pixel n
        auto hamt = [](int t) {
            const float a = (t / 3 == 1) ? 1.f : 0.08f;
            const float b = (t % 3 == 1) ? 1.f : 0.08f;
            return a * b;
        };
        const int nval = (fq < 2) ? 4 : (fq == 2 ? 1 : 0);
        float e0 = 0, e1 = 0, e2 = 0, e3 = 0, ssum = 0;
        if (nval >= 1) { e0 = __expf(acc[0] + bq[0]) * hamt(fq * 4 + 0); ssum += e0; }
        if (nval >= 4) { e1 = __expf(acc[1] + bq[1]) * hamt(fq * 4 + 1); ssum += e1;
                         e2 = __expf(acc[2] + bq[2]) * hamt(fq * 4 + 2); ssum += e2;
                         e3 = __expf(acc[3] + bq[3]) * hamt(fq * 4 + 3); ssum += e3; }
        ssum += __shfl_xor(ssum, 16);
        ssum += __shfl_xor(ssum, 32);
        const float inv = 1.0f / ssum;

        // broadcast 9 taps to every lane of pixel n (bf16-packed, 5 shuffles)
        const unsigned p01 = pkbf(e0 * inv, e1 * inv);
        const unsigned p23 = pkbf(e2 * inv, e3 * inv);
        const unsigned q0 = (unsigned)__shfl((int)p01, n);
        const unsigned q1 = (unsigned)__shfl((int)p23, n);
        const unsigned q2 = (unsigned)__shfl((int)p01, 16 + n);
        const unsigned q3 = (unsigned)__shfl((int)p23, 16 + n);
        const unsigned q4 = (unsigned)__shfl((int)p01, 32 + n);
        float mk[9];
        { float2v m;
          m = unpk(q0); mk[0] = m.x; mk[1] = m.y;
          m = unpk(q1); mk[2] = m.x; mk[3] = m.y;
          m = unpk(q2); mk[4] = m.x; mk[5] = m.y;
          m = unpk(q3); mk[6] = m.x; mk[7] = m.y;
          mk[8] = unpk(q4).x; }

        // carafe from registers: lane covers ch {8fq..}+{32+8fq..} of pixel n
        float2v l[8];
#pragma unroll
        for (int q = 0; q < 8; ++q) l[q] = (float2v)0.f;
#pragma unroll
        for (int t = 0; t < 9; ++t) {
            const float mt = mk[t];
            const uint4v b0 = *(const uint4v*)&bfr[2 * t];
            const uint4v b1 = *(const uint4v*)&bfr[2 * t + 1];
#pragma unroll
            for (int q = 0; q < 4; ++q) {
                l[q]     += mt * unpk(b0[q]);
                l[q + 4] += mt * unpk(b1[q]);
            }
        }
        const uint4v c0 = *(const uint4v*)&bfr[8];
        const uint4v c1 = *(const uint4v*)&bfr[9];
        float* ob = out + (size_t)bz * CCH * hw + (size_t)h * IW + w
                  + (size_t)(8 * fq) * hw;
#pragma unroll
        for (int q = 0; q < 4; ++q) {
            const float2v oe = 2.f * unpk(c0[q]) - l[q];
            const float2v oo = 2.f * unpk(c1[q]) - l[q + 4];
            ob[(size_t)(2 * q) * hw]          = oe.x;
            ob[(size_t)(2 * q + 1) * hw]      = oe.y;
            ob[(size_t)(32 + 2 * q) * hw]     = oo.x;
            ob[(size_t)(32 + 2 * q + 1) * hw] = oo.y;
        }
    }
}

extern "C" void kernel_launch(void* const* d_in, const int* in_sizes, int n_in,
                              void* d_out, int out_size, void* d_ws, size_t ws_size,
                              hipStream_t stream) {
    const float* x    = (const float*)d_in[0];
    const float* Wg   = (const float*)d_in[1];
    const float* bias = (const float*)d_in[2];
    float* out        = (float*)d_out;
    const int B = in_sizes[0] / (CCH * IH * IW);
    const int nblk = B * 256;   // 2048 for B=8

    if (ws_size >= 18 * 64 * 16) {
        unsigned short* wsp = (unsigned short*)d_ws;
        ahpf_prep<<<5, 256, 0, stream>>>(Wg, wsp);
        ahpf_kernel<true><<<nblk, 64, 0, stream>>>(x, Wg, bias, out, wsp);
    } else {
        ahpf_kernel<false><<<nblk, 64, 0, stream>>>(x, Wg, bias, out, nullptr);
    }
}